// Round 7
// baseline (22.648 us; speedup 1.0000x reference)
//
#include <hip/hip_runtime.h>

#define D_ 32
#define H_ 128
#define B_ 32
#define NSTEP 2
#define DT 0.5f          // exact in f32
#define NPRE 32          // precompute blocks (blocks 0..31); solvers are 32..63
#define MAGIC 0x13579BDFu

template<int N> struct IC { static constexpr int v = N; };

// ---- DPP cross-lane reduction (no DS ops) ----
template<int CTRL>
__device__ __forceinline__ float qadd(float v) {
  int t = __builtin_amdgcn_update_dpp(0, __builtin_bit_cast(int, v), CTRL, 0xF, 0xF, true);
  return v + __builtin_bit_cast(float, t);
}
__device__ __forceinline__ float xor4add(float v) {
  int s = __builtin_bit_cast(int, v);
  int t = __builtin_amdgcn_update_dpp(0, s, 0x12C, 0xF, 0x5, true);  // ror:12 -> lanes 0-3,8-11
  t     = __builtin_amdgcn_update_dpp(t, s, 0x124, 0xF, 0xA, true);  // ror:4  -> lanes 4-7,12-15
  return v + __builtin_bit_cast(float, t);
}
__device__ __forceinline__ float red8(float v) { return xor4add(qadd<0x4E>(qadd<0xB1>(v))); }
__device__ __forceinline__ float red4(float v) { return qadd<0x4E>(qadd<0xB1>(v)); }

// Fused kernel.
//  Blocks 0..NPRE-1 : precompute P[i][k] = sum_d W1[i][d]*W3[d][k], G[k][i] = W2[k][i]*P[i][k],
//                     q[i] = sum_d W1[i][d]*b3[d]; release per-block flag.
//  Blocks NPRE..    : per-item RK4 solver; polls flags (acquire) after its independent prologue.
//  Replay race on P/G/q is benign: values are input-deterministic, rewrites are bit-identical.
__global__ __launch_bounds__(512)
void node_fused(const float* __restrict__ x,
                const float* __restrict__ W1, const float* __restrict__ b1,
                const float* __restrict__ W2, const float* __restrict__ b2,
                const float* __restrict__ W3, const float* __restrict__ b3,
                float* __restrict__ G, float* __restrict__ P,
                float* __restrict__ q, unsigned int* __restrict__ flags,
                float* __restrict__ out) {
  const int tid = threadIdx.x;

  // ================= precompute blocks =================
  if (blockIdx.x < NPRE) {
    const int p  = blockIdx.x;
    const int il = tid >> 7;            // 0..3
    const int k  = tid & 127;           // layer-2 index
    const int i  = 4*p + il;            // layer-1 index
    const float* w1r = W1 + i*(D_+1);
    float m = 0.f;
    #pragma unroll
    for (int d = 0; d < D_; ++d) m += w1r[d] * W3[d*H_ + k];
    P[i*H_ + k] = m;
    G[k*H_ + i] = W2[k*H_ + i] * m;
    if (k == 0) {
      float s = 0.f;
      #pragma unroll
      for (int d = 0; d < D_; ++d) s += w1r[d] * b3[d];
      q[i] = s;
    }
    __threadfence();        // make P/G/q agent-visible before the flag
    __syncthreads();
    if (tid == 0)
      __hip_atomic_store(&flags[p], MAGIC, __ATOMIC_RELEASE, __HIP_MEMORY_SCOPE_AGENT);
    return;
  }

  // ================= solver blocks =================
  const int b = blockIdx.x - NPRE;

  __shared__ __align__(16) float h1_l[H_];   // reused as hacc staging in epilogue
  __shared__ __align__(16) float d1_l[H_];
  __shared__ __align__(16) float h2_l[H_];
  __shared__ __align__(16) float d2_l[H_];
  __shared__ __align__(16) float gv_l[H_];

  float wA[64];    // phase P tile (waves 0-3: W2, waves 4-7: G)
  float wP[64];    // phase Q tile of P (waves 0-3)
  float wB3[32];   // epilogue W3 quarter-row (waves 4-5)
  float rb3 = 0.f;

  const int lt = tid & 255;
  const int rg = lt >> 3;          // group: rows 4rg..4rg+3
  const int cg = lt & 7;           // 8 threads per group, 16 cols each
  const int myrow = 4*rg + cg;     // owned row (valid when cg < 4)
  const int r3 = (tid - 256) >> 2; // W3 row (tid in [256,384))
  const int c3 = tid & 3;

  float zu = 0.f, zuacc = 0.f;                       // u-space state (waves 0-3, cg<4)
  float hacc = 0.f;                                  // sum of wS*h2 over all stages (owners)
  float rqq = 0.f, rb1 = 0.f, w1t = 0.f, rb2 = 0.f;  // owner row constants
  float zr = 0.f;                                    // x0 (waves 4-5, for epilogue)
  float tracc = 0.f;                                 // trace partials (wave 6)

  auto tanh_f = [](float u) {
    float e = exp2f(2.885390081777927f * u);
    return 1.0f - 2.0f * __builtin_amdgcn_rcpf(e + 1.0f);
  };

  // ---- P/G-independent prologue (overlaps with precompute blocks) ----
  if (tid < 256) {
    // wA = W2 tile (rotated for bank-clean LDS reads)
    #pragma unroll
    for (int j = 0; j < 4; ++j) {
      const float* p = W2 + (4*rg + j)*H_ + cg*16;
      #pragma unroll
      for (int k = 0; k < 4; ++k) {
        const int src = 4*((k + cg) & 3);
        #pragma unroll
        for (int e = 0; e < 4; ++e) wA[16*j + 4*k + e] = p[src + e];
      }
    }
    if (cg < 4) {
      rb1 = b1[myrow];
      rb2 = b2[myrow];
      w1t = W1[myrow*(D_+1) + D_];
      // init: zu = W1x . x0 ; seed h1/d1 at t=0 (t_eff = 1)
      float zu0 = 0.f;
      const float* w1r = W1 + myrow*(D_+1);
      const float* xb  = x + b*D_;
      #pragma unroll
      for (int d = 0; d < D_; ++d) zu0 += w1r[d] * xb[d];
      zu = zu0;
      float h = tanh_f(zu0 + w1t + rb1);
      h1_l[myrow] = h;
      d1_l[myrow] = 1.f - h*h;
    }
  } else if (tid < 384) {
    const float* p = W3 + r3*H_ + c3*32;
    #pragma unroll
    for (int jj = 0; jj < 8; ++jj) {
      const int src = 4*((jj + 2*c3) & 7);
      #pragma unroll
      for (int e = 0; e < 4; ++e) wB3[4*jj + e] = p[src + e];
    }
    rb3 = b3[r3];
    zr  = x[b*D_ + r3];
  }

  // ---- wait for precompute ----
  if (tid < NPRE) {
    while (__hip_atomic_load(&flags[tid], __ATOMIC_ACQUIRE, __HIP_MEMORY_SCOPE_AGENT) != MAGIC)
      __builtin_amdgcn_s_sleep(1);
  }
  __syncthreads();

  // ---- P/G-dependent loads ----
  if (tid < 256) {
    #pragma unroll
    for (int j = 0; j < 4; ++j) {
      const float* p = P + (4*rg + j)*H_ + cg*16;
      #pragma unroll
      for (int k = 0; k < 4; ++k) {
        const int src = 4*((k + cg) & 3);
        #pragma unroll
        for (int e = 0; e < 4; ++e) wP[16*j + 4*k + e] = p[src + e];
      }
    }
    if (cg < 4) rqq = q[myrow];
  } else {
    #pragma unroll
    for (int j = 0; j < 4; ++j) {
      const float* p = G + (4*rg + j)*H_ + cg*16;
      #pragma unroll
      for (int k = 0; k < 4; ++k) {
        const int src = 4*((k + cg) & 3);
        #pragma unroll
        for (int e = 0; e < 4; ++e) wA[16*j + 4*k + e] = p[src + e];
      }
    }
  }
  __syncthreads();

  // Phase P (stage S): u2 = W2 h1 (waves 0-3) || gv = G d1 (waves 4-7).
  // Owners also accumulate hacc += wS*h2 (deferred linear x-quadrature).
  auto phaseP = [&](auto Sc) {
    constexpr int S = decltype(Sc)::v;
    constexpr float wS = (S==0 || S==3) ? 1.f : 2.f;
    const float* vec  = (tid < 256) ? h1_l : d1_l;
    const float* base = vec + cg*16;
    float4 va[4];
    #pragma unroll
    for (int k = 0; k < 4; ++k)
      va[k] = *reinterpret_cast<const float4*>(base + 4*((k + cg) & 3));
    float accv[4];
    #pragma unroll
    for (int j = 0; j < 4; ++j) {
      float s0=0.f, s1=0.f, s2=0.f, s3=0.f;
      #pragma unroll
      for (int k = 0; k < 4; ++k) {
        s0 += wA[16*j+4*k+0]*va[k].x;
        s1 += wA[16*j+4*k+1]*va[k].y;
        s2 += wA[16*j+4*k+2]*va[k].z;
        s3 += wA[16*j+4*k+3]*va[k].w;
      }
      accv[j] = red8((s0+s1)+(s2+s3));
    }
    if (cg < 4) {
      float a = accv[0];
      a = (cg == 1) ? accv[1] : a;
      a = (cg == 2) ? accv[2] : a;
      a = (cg == 3) ? accv[3] : a;
      if (tid < 256) {
        float h = tanh_f(a + rb2);
        h2_l[myrow] = h;
        d2_l[myrow] = 1.f - h*h;
        hacc += wS * h;
      } else {
        gv_l[myrow] = a;
      }
    }
  };

  // Phase Q (RK4 stage S of step it):
  //  waves 0-3: Ku = -(P h2 + q); owner lanes advance u-state, emit next h1/d1
  //  wave  6  : trace partial (d2 . gv), accumulated per-lane, reduced once at end
  auto phaseQ = [&](auto Sc, int it) {
    constexpr int S = decltype(Sc)::v;
    constexpr float wS = (S==0 || S==3) ? 1.f : 2.f;
    if (tid < 256) {
      const float* base = h2_l + cg*16;
      float4 va[4];
      #pragma unroll
      for (int k = 0; k < 4; ++k)
        va[k] = *reinterpret_cast<const float4*>(base + 4*((k + cg) & 3));
      float accv[4];
      #pragma unroll
      for (int j = 0; j < 4; ++j) {
        float s0=0.f, s1=0.f, s2=0.f, s3=0.f;
        #pragma unroll
        for (int k = 0; k < 4; ++k) {
          s0 += wP[16*j+4*k+0]*va[k].x;
          s1 += wP[16*j+4*k+1]*va[k].y;
          s2 += wP[16*j+4*k+2]*va[k].z;
          s3 += wP[16*j+4*k+3]*va[k].w;
        }
        accv[j] = red8((s0+s1)+(s2+s3));
      }
      if (cg < 4) {
        float a = accv[0];
        a = (cg == 1) ? accv[1] : a;
        a = (cg == 2) ? accv[2] : a;
        a = (cg == 3) ? accv[3] : a;
        const float Ku = -(a + rqq);
        zuacc += wS * Ku;
        float zb;
        if constexpr (S == 0 || S == 1) zb = zu + 0.5f*DT*Ku;
        else if constexpr (S == 2)      zb = zu + DT*Ku;
        else { zu += (DT/6.0f)*zuacc; zuacc = 0.f; zb = zu; }
        const float fit = (float)it;
        const float te = (S < 2) ? (1.0f - (fit + 0.5f)*DT)
                                 : (1.0f - (fit + 1.0f)*DT);
        const float h = tanh_f(zb + w1t*te + rb1);
        h1_l[myrow] = h;
        d1_l[myrow] = 1.f - h*h;
      }
    } else if (tid >= 384 && tid < 448) {
      const int l = tid - 384;
      tracc += wS * (d2_l[l]*gv_l[l] + d2_l[l+64]*gv_l[l+64]);
    }
  };

  #pragma unroll 1
  for (int it = 0; it < NSTEP; ++it) {
    phaseP(IC<0>{}); __syncthreads(); phaseQ(IC<0>{}, it); __syncthreads();
    phaseP(IC<1>{}); __syncthreads(); phaseQ(IC<1>{}, it); __syncthreads();
    phaseP(IC<2>{}); __syncthreads(); phaseQ(IC<2>{}, it); __syncthreads();
    phaseP(IC<3>{}); __syncthreads(); phaseQ(IC<3>{}, it); __syncthreads();
  }

  // ---- epilogue ----
  // x(1) = x0 - (DT/6) * W3 . hacc_total - b3   (linearity of W3)
  if (tid < 256 && cg < 4) h1_l[myrow] = hacc;
  __syncthreads();
  if (tid >= 256 && tid < 384) {
    const float* base = h1_l + c3*32;
    float s0=0.f, s1=0.f, s2=0.f, s3=0.f;
    #pragma unroll
    for (int jj = 0; jj < 8; ++jj) {
      float4 v = *reinterpret_cast<const float4*>(base + 4*((jj + 2*c3) & 7));
      s0 += wB3[4*jj+0]*v.x;
      s1 += wB3[4*jj+1]*v.y;
      s2 += wB3[4*jj+2]*v.z;
      s3 += wB3[4*jj+3]*v.w;
    }
    float acc = red4((s0+s1)+(s2+s3));
    if (c3 == 0) out[b*D_ + r3] = zr - (DT/6.0f)*acc - rb3;
  }
  if (tid >= 384 && tid < 448) {
    float v = tracc;
    #pragma unroll
    for (int m = 1; m < 64; m <<= 1) v += __shfl_xor(v, m);
    if (tid == 384) out[B_*D_ + b] = -(DT/6.0f) * v;   // log_px = -∫ trace
  }
}

extern "C" void kernel_launch(void* const* d_in, const int* in_sizes, int n_in,
                              void* d_out, int out_size, void* d_ws, size_t ws_size,
                              hipStream_t stream) {
  const float* x  = (const float*)d_in[0];
  const float* W1 = (const float*)d_in[1];
  const float* b1 = (const float*)d_in[2];
  const float* W2 = (const float*)d_in[3];
  const float* b2 = (const float*)d_in[4];
  const float* W3 = (const float*)d_in[5];
  const float* b3 = (const float*)d_in[6];
  float* out = (float*)d_out;
  float* G = (float*)d_ws;                 // 16384 f
  float* P = G + H_*H_;                    // 16384 f
  float* q = P + H_*H_;                    // 128 f
  unsigned int* flags = (unsigned int*)(q + H_);  // 32 u32

  hipLaunchKernelGGL(node_fused, dim3(NPRE + B_), dim3(512), 0, stream,
                     x, W1, b1, W2, b2, W3, b3, G, P, q, flags, out);
}

// Round 8
// 16.425 us; speedup vs baseline: 1.3788x; 1.3788x over previous
//
#include <hip/hip_runtime.h>

#define D_ 32
#define H_ 128
#define B_ 32
#define DT 1.0f   // single RK4 step over [0,1]

template<int N> struct IC { static constexpr int v = N; };

// ---- DPP cross-lane reduction (no DS ops) ----
template<int CTRL>
__device__ __forceinline__ float qadd(float v) {
  int t = __builtin_amdgcn_update_dpp(0, __builtin_bit_cast(int, v), CTRL, 0xF, 0xF, true);
  return v + __builtin_bit_cast(float, t);
}
__device__ __forceinline__ float xor4add(float v) {
  int s = __builtin_bit_cast(int, v);
  int t = __builtin_amdgcn_update_dpp(0, s, 0x12C, 0xF, 0x5, true);  // ror:12 -> lanes 0-3,8-11
  t     = __builtin_amdgcn_update_dpp(t, s, 0x124, 0xF, 0xA, true);  // ror:4  -> lanes 4-7,12-15
  return v + __builtin_bit_cast(float, t);
}
__device__ __forceinline__ float red8(float v) { return xor4add(qadd<0x4E>(qadd<0xB1>(v))); }
__device__ __forceinline__ float red4(float v) { return qadd<0x4E>(qadd<0xB1>(v)); }

// Precompute (input-independent):
//   P[i][k] = sum_d W1[i][d] * W3[d][k]  -> u-space propagation matrix
//   G[k][i] = W2[k][i] * P[i][k]         -> trace(J) = d2^T (G d1)
//   q[i]    = sum_d W1[i][d] * b3[d]
__global__ void g_precompute(const float* __restrict__ W1, const float* __restrict__ W2,
                             const float* __restrict__ W3, const float* __restrict__ b3,
                             float* __restrict__ G, float* __restrict__ P,
                             float* __restrict__ q) {
  const int i = blockIdx.x;
  const int k = threadIdx.x;
  const float* w1r = W1 + i*(D_+1);
  float m = 0.f;
  #pragma unroll
  for (int d = 0; d < D_; ++d) m += w1r[d] * W3[d*H_ + k];
  P[i*H_ + k] = m;
  G[k*H_ + i] = W2[k*H_ + i] * m;
  if (k == 0) {
    float s = 0.f;
    #pragma unroll
    for (int d = 0; d < D_; ++d) s += w1r[d] * b3[d];
    q[i] = s;
  }
}

__global__ __launch_bounds__(512)
void node_solve(const float* __restrict__ x,
                const float* __restrict__ W1, const float* __restrict__ b1,
                const float* __restrict__ W2, const float* __restrict__ b2,
                const float* __restrict__ W3, const float* __restrict__ b3,
                const float* __restrict__ G, const float* __restrict__ P,
                const float* __restrict__ q, float* __restrict__ out) {
  const int tid = threadIdx.x;
  const int b   = blockIdx.x;

  __shared__ __align__(16) float h1_l[H_];   // reused as hacc staging in epilogue
  __shared__ __align__(16) float d1_l[H_];
  __shared__ __align__(16) float h2_l[H_];
  __shared__ __align__(16) float d2_l[H_];
  __shared__ __align__(16) float gv_l[H_];

  float wA[64];    // phase P tile (waves 0-3: W2, waves 4-7: G), chunk-rotated
  float wP[64];    // phase Q tile of P (waves 0-3)
  float wB3[32];   // epilogue W3 quarter-row (waves 4-5), chunk-rotated
  float rb3 = 0.f;

  const int lt = tid & 255;
  const int rg = lt >> 3;          // group: rows 4rg..4rg+3
  const int cg = lt & 7;           // 8 threads per group, 16 cols each
  const int myrow = 4*rg + cg;     // owned row (valid when cg < 4)
  const int r3 = (tid - 256) >> 2; // W3 row (tid in [256,384))
  const int c3 = tid & 3;

  float zu = 0.f, zuacc = 0.f;                       // u-space state (waves 0-3, cg<4)
  float hacc = 0.f;                                  // sum of wS*h2 over stages (owners)
  float rqq = 0.f, rb1 = 0.f, w1t = 0.f, rb2 = 0.f;  // owner row constants
  float zr = 0.f;                                    // x0 (waves 4-5, for epilogue)
  float tracc = 0.f;                                 // trace partials (wave 6)

  auto tanh_f = [](float u) {
    float e = exp2f(2.885390081777927f * u);
    return 1.0f - 2.0f * __builtin_amdgcn_rcpf(e + 1.0f);
  };

  // ---- weight loads (rotated for bank-clean LDS reads later) ----
  {
    const float* Wsrc = (tid < 256) ? W2 : G;
    #pragma unroll
    for (int j = 0; j < 4; ++j) {
      const float* p = Wsrc + (4*rg + j)*H_ + cg*16;
      #pragma unroll
      for (int k = 0; k < 4; ++k) {
        const int src = 4*((k + cg) & 3);
        #pragma unroll
        for (int e = 0; e < 4; ++e) wA[16*j + 4*k + e] = p[src + e];
      }
    }
  }
  if (tid < 256) {
    #pragma unroll
    for (int j = 0; j < 4; ++j) {
      const float* p = P + (4*rg + j)*H_ + cg*16;
      #pragma unroll
      for (int k = 0; k < 4; ++k) {
        const int src = 4*((k + cg) & 3);
        #pragma unroll
        for (int e = 0; e < 4; ++e) wP[16*j + 4*k + e] = p[src + e];
      }
    }
    if (cg < 4) {
      rqq = q[myrow];
      rb1 = b1[myrow];
      rb2 = b2[myrow];
      w1t = W1[myrow*(D_+1) + D_];
      // init: zu = W1x . x0 ; seed h1/d1 at t=0 (t_eff = 1)
      float zu0 = 0.f;
      const float* w1r = W1 + myrow*(D_+1);
      const float* xb  = x + b*D_;
      #pragma unroll
      for (int d = 0; d < D_; ++d) zu0 += w1r[d] * xb[d];
      zu = zu0;
      float h = tanh_f(zu0 + w1t + rb1);
      h1_l[myrow] = h;
      d1_l[myrow] = 1.f - h*h;
    }
  } else if (tid < 384) {
    const float* p = W3 + r3*H_ + c3*32;
    #pragma unroll
    for (int jj = 0; jj < 8; ++jj) {
      const int src = 4*((jj + 2*c3) & 7);
      #pragma unroll
      for (int e = 0; e < 4; ++e) wB3[4*jj + e] = p[src + e];
    }
    rb3 = b3[r3];
    zr  = x[b*D_ + r3];
  }
  __syncthreads();

  // Phase P (stage S): u2 = W2 h1 (waves 0-3) || gv = G d1 (waves 4-7).
  // Owners also accumulate hacc += wS*h2 (deferred linear x-quadrature).
  auto phaseP = [&](auto Sc) {
    constexpr int S = decltype(Sc)::v;
    constexpr float wS = (S==0 || S==3) ? 1.f : 2.f;
    const float* vec  = (tid < 256) ? h1_l : d1_l;
    const float* base = vec + cg*16;
    float4 va[4];
    #pragma unroll
    for (int k = 0; k < 4; ++k)
      va[k] = *reinterpret_cast<const float4*>(base + 4*((k + cg) & 3));
    float accv[4];
    #pragma unroll
    for (int j = 0; j < 4; ++j) {
      float s0=0.f, s1=0.f, s2=0.f, s3=0.f;
      #pragma unroll
      for (int k = 0; k < 4; ++k) {
        s0 += wA[16*j+4*k+0]*va[k].x;
        s1 += wA[16*j+4*k+1]*va[k].y;
        s2 += wA[16*j+4*k+2]*va[k].z;
        s3 += wA[16*j+4*k+3]*va[k].w;
      }
      accv[j] = red8((s0+s1)+(s2+s3));
    }
    if (cg < 4) {
      float a = accv[0];
      a = (cg == 1) ? accv[1] : a;
      a = (cg == 2) ? accv[2] : a;
      a = (cg == 3) ? accv[3] : a;
      if (tid < 256) {
        float h = tanh_f(a + rb2);
        h2_l[myrow] = h;
        d2_l[myrow] = 1.f - h*h;
        hacc += wS * h;
      } else {
        gv_l[myrow] = a;
      }
    }
  };

  // Phase Q (RK4 stage S, S<3): waves 0-3 advance u-state + emit next h1/d1;
  // wave 6 accumulates trace partial (d2 . gv).
  auto phaseQ = [&](auto Sc) {
    constexpr int S = decltype(Sc)::v;
    constexpr float wS = (S==0) ? 1.f : 2.f;
    if (tid < 256) {
      const float* base = h2_l + cg*16;
      float4 va[4];
      #pragma unroll
      for (int k = 0; k < 4; ++k)
        va[k] = *reinterpret_cast<const float4*>(base + 4*((k + cg) & 3));
      float accv[4];
      #pragma unroll
      for (int j = 0; j < 4; ++j) {
        float s0=0.f, s1=0.f, s2=0.f, s3=0.f;
        #pragma unroll
        for (int k = 0; k < 4; ++k) {
          s0 += wP[16*j+4*k+0]*va[k].x;
          s1 += wP[16*j+4*k+1]*va[k].y;
          s2 += wP[16*j+4*k+2]*va[k].z;
          s3 += wP[16*j+4*k+3]*va[k].w;
        }
        accv[j] = red8((s0+s1)+(s2+s3));
      }
      if (cg < 4) {
        float a = accv[0];
        a = (cg == 1) ? accv[1] : a;
        a = (cg == 2) ? accv[2] : a;
        a = (cg == 3) ? accv[3] : a;
        const float Ku = -(a + rqq);
        zuacc += wS * Ku;
        // stage input: S=0,1 -> z + dt/2 * k ; S=2 -> z + dt * k
        const float zb = zu + ((S == 2) ? DT : 0.5f*DT) * Ku;
        const float te = (S < 2) ? (1.0f - 0.5f*DT) : (1.0f - DT);  // t_eff of next stage
        const float h = tanh_f(zb + w1t*te + rb1);
        h1_l[myrow] = h;
        d1_l[myrow] = 1.f - h*h;
      }
    } else if (tid >= 384 && tid < 448) {
      const int l = tid - 384;
      tracc += wS * (d2_l[l]*gv_l[l] + d2_l[l+64]*gv_l[l+64]);
    }
  };

  // ---- single RK4 step over [0,1]; stage 3 needs no u-advance (x & log_px
  //      come from the deferred W3 quadrature and the trace integral) ----
  phaseP(IC<0>{}); __syncthreads(); phaseQ(IC<0>{}); __syncthreads();
  phaseP(IC<1>{}); __syncthreads(); phaseQ(IC<1>{}); __syncthreads();
  phaseP(IC<2>{}); __syncthreads(); phaseQ(IC<2>{}); __syncthreads();
  phaseP(IC<3>{}); __syncthreads();

  // stage-3 trace tap (weight 1) + hacc staging for the epilogue matvec
  if (tid >= 384 && tid < 448) {
    const int l = tid - 384;
    tracc += d2_l[l]*gv_l[l] + d2_l[l+64]*gv_l[l+64];
  }
  if (tid < 256 && cg < 4) h1_l[myrow] = hacc;
  __syncthreads();

  // ---- epilogue ----
  // x(1) = x0 - (DT/6) * W3 . hacc_total - b3   (linearity of W3; sum of wS = 6)
  if (tid >= 256 && tid < 384) {
    const float* base = h1_l + c3*32;
    float s0=0.f, s1=0.f, s2=0.f, s3=0.f;
    #pragma unroll
    for (int jj = 0; jj < 8; ++jj) {
      float4 v = *reinterpret_cast<const float4*>(base + 4*((jj + 2*c3) & 7));
      s0 += wB3[4*jj+0]*v.x;
      s1 += wB3[4*jj+1]*v.y;
      s2 += wB3[4*jj+2]*v.z;
      s3 += wB3[4*jj+3]*v.w;
    }
    float acc = red4((s0+s1)+(s2+s3));
    if (c3 == 0) out[b*D_ + r3] = zr - (DT/6.0f)*acc - rb3;
  }
  if (tid >= 384 && tid < 448) {
    float v = tracc;
    #pragma unroll
    for (int m = 1; m < 64; m <<= 1) v += __shfl_xor(v, m);
    if (tid == 384) out[B_*D_ + b] = -(DT/6.0f) * v;   // log_px = -∫ trace
  }
}

extern "C" void kernel_launch(void* const* d_in, const int* in_sizes, int n_in,
                              void* d_out, int out_size, void* d_ws, size_t ws_size,
                              hipStream_t stream) {
  const float* x  = (const float*)d_in[0];
  const float* W1 = (const float*)d_in[1];
  const float* b1 = (const float*)d_in[2];
  const float* W2 = (const float*)d_in[3];
  const float* b2 = (const float*)d_in[4];
  const float* W3 = (const float*)d_in[5];
  const float* b3 = (const float*)d_in[6];
  float* out = (float*)d_out;
  float* G = (float*)d_ws;
  float* P = G + H_*H_;
  float* q = P + H_*H_;

  hipLaunchKernelGGL(g_precompute, dim3(H_), dim3(H_), 0, stream, W1, W2, W3, b3, G, P, q);
  hipLaunchKernelGGL(node_solve, dim3(B_), dim3(512), 0, stream,
                     x, W1, b1, W2, b2, W3, b3, G, P, q, out);
}